// Round 3
// baseline (225.634 us; speedup 1.0000x reference)
//
#include <hip/hip_runtime.h>
#include <math.h>

#define NB 32    // batch
#define NS 128   // steps
#define NI 256   // in_dim
#define NC 128   // num capsules
#define ND 64    // dim capsule

#define L4 9.210340371976184f  // ln(10000)

// ---------------------------------------------------------------------------
// k_prep:
//   blocks [0,1024):      M[b,s,d] = sum_i u*W ; U[b,s] = sum_i u
//   blocks [1024,5120):   pe2n[n][s][d]  (n-major trig table)
//   blocks [5120,5152):   PE1[n][d]
// ---------------------------------------------------------------------------
__global__ __launch_bounds__(256) void k_prep(const float* __restrict__ u,
                                              const float* __restrict__ W,
                                              float* __restrict__ M,
                                              float* __restrict__ U,
                                              float* __restrict__ PE1,
                                              float* __restrict__ pe2n) {
    int blk = blockIdx.x;
    int t = threadIdx.x;
    if (blk < 1024) {
        int row = blk * 4 + (t >> 6);   // b*NS + s
        int d = t & 63;
        const float* ur = u + row * NI;
        float acc = 0.f, rs = 0.f;
#pragma unroll 4
        for (int i = 0; i < NI; ++i) {
            float v = ur[i];
            acc = fmaf(v, W[i * ND + d], acc);
            rs += v;
        }
        M[row * ND + d] = acc;
        if (d == 0) U[row] = rs;
    } else if (blk < 1024 + 4096) {
        int idx = (blk - 1024) * 256 + t;          // 1M elems
        int n = idx >> 13, s = (idx >> 6) & 127, d = idx & 63;
        int k2 = (n << 5) + (d >> 1);
        float g = __expf(-L4 * (float)k2 * (1.f / 4096.f));
        float sv, cv;
        __sincosf((float)s * g, &sv, &cv);
        pe2n[idx] = (d & 1) ? cv : sv;
    } else {
        int idx = (blk - 1024 - 4096) * 256 + t;   // 8192 elems
        int n = idx >> 6, d = idx & 63;
        float ang = (float)n * __expf(-L4 * (float)(d >> 1) * (1.f / 32.f));
        float sv, cv;
        __sincosf(ang, &sv, &cv);
        PE1[idx] = (d & 1) ? cv : sv;
    }
}

// ---------------------------------------------------------------------------
// kA: fused routing step. Block = 2 b x 8 n; 8 groups of 32 lanes, group g
// owns n = n0+g for BOTH b's (lane j = d-pair 2j).
// Pass 1: out[b,n,:] = squash( sum_s c*(M+pe2n) + PE1*(sum_s c*U) ), write og.
// Pass 2 (if !last): bl[b,s,n] = sum_d out*(M+pe2n) + PU*U[s]  (butterfly
// reduce over the 32 d-pair lanes per s; PU = sum_d out*PE1 in-register).
// grid = 256 blocks (16 btiles x 16 ntiles), 256 threads.
// ---------------------------------------------------------------------------
__global__ __launch_bounds__(256) void kA(const float* __restrict__ M,
                                          const float* __restrict__ U,
                                          const float* __restrict__ PE1,
                                          const float* __restrict__ pe2n,
                                          const float* __restrict__ cg,
                                          const float* __restrict__ mask,
                                          float* __restrict__ og,
                                          float* __restrict__ bl,
                                          int first, int last) {
    int blk = blockIdx.x;
    int b0 = (blk >> 4) * 2;
    int n0 = (blk & 15) * 8;
    int t = threadIdx.x;

    __shared__ float ct[2][NS][8];   // c[b][s][n-tile]
    __shared__ float Us[2][NS];
    __shared__ float pe1t[8][ND];

    // ---- stage c (8 KB), U (1 KB), PE1 tile (2 KB) ----
#pragma unroll
    for (int k = 0; k < 4; ++k) {
        int i = k * 256 + t;                 // [0,1024)
        int bh = i >> 9, s = (i >> 2) & 127, q = i & 3;
        if (first) {
            float v = mask[(b0 + bh) * NS + s] * (1.f / 128.f);
            ct[bh][s][2 * q] = v; ct[bh][s][2 * q + 1] = v;
        } else {
            float2 cv = *(const float2*)(cg + ((b0 + bh) * NS + s) * NC + n0 + 2 * q);
            ct[bh][s][2 * q] = cv.x; ct[bh][s][2 * q + 1] = cv.y;
        }
    }
    { int bh = t >> 7, s = t & 127; Us[bh][s] = U[(b0 + bh) * NS + s]; }
#pragma unroll
    for (int k = 0; k < 2; ++k) {
        int i = k * 256 + t;                 // [0,512)
        pe1t[i >> 6][i & 63] = PE1[(n0 + (i >> 6)) * ND + (i & 63)];
    }
    __syncthreads();

    int g = t >> 5, j = t & 31;
    int n = n0 + g, d0 = 2 * j;

    const float* Pp  = pe2n + (n * NS) * ND + d0;
    const float* Mp0 = M + ((b0 + 0) * NS) * ND + d0;
    const float* Mp1 = M + ((b0 + 1) * NS) * ND + d0;

    // ---- pass 1: accumulate out_pre over s ----
    float ax0 = 0.f, ay0 = 0.f, ax1 = 0.f, ay1 = 0.f;
#pragma unroll 4
    for (int s = 0; s < NS; ++s) {
        float2 p  = *(const float2*)(Pp  + s * ND);
        float2 m0 = *(const float2*)(Mp0 + s * ND);
        float2 m1 = *(const float2*)(Mp1 + s * ND);
        float c0 = ct[0][s][g], c1 = ct[1][s][g];
        ax0 = fmaf(c0, m0.x + p.x, ax0);
        ay0 = fmaf(c0, m0.y + p.y, ay0);
        ax1 = fmaf(c1, m1.x + p.x, ax1);
        ay1 = fmaf(c1, m1.y + p.y, ay1);
    }

    // CU[bh] = sum_s c*U  (32-lane butterfly)
    float cu0 = 0.f, cu1 = 0.f;
#pragma unroll
    for (int k = 0; k < 4; ++k) {
        int s = j + 32 * k;
        cu0 += ct[0][s][g] * Us[0][s];
        cu1 += ct[1][s][g] * Us[1][s];
    }
#pragma unroll
    for (int o = 16; o > 0; o >>= 1) { cu0 += __shfl_xor(cu0, o); cu1 += __shfl_xor(cu1, o); }

    float p1x = pe1t[g][d0], p1y = pe1t[g][d0 + 1];

    float ox0 = fmaf(cu0, p1x, ax0), oy0 = fmaf(cu0, p1y, ay0);
    float ox1 = fmaf(cu1, p1x, ax1), oy1 = fmaf(cu1, p1y, ay1);

    float ss0 = ox0 * ox0 + oy0 * oy0;
    float ss1 = ox1 * ox1 + oy1 * oy1;
#pragma unroll
    for (int o = 16; o > 0; o >>= 1) { ss0 += __shfl_xor(ss0, o); ss1 += __shfl_xor(ss1, o); }
    float sc0 = ss0 / (1.f + ss0) * rsqrtf(ss0 + 1e-7f);
    float sc1 = ss1 / (1.f + ss1) * rsqrtf(ss1 + 1e-7f);
    ox0 *= sc0; oy0 *= sc0; ox1 *= sc1; oy1 *= sc1;

    *(float2*)(og + ((b0 + 0) * NC + n) * ND + d0) = make_float2(ox0, oy0);
    *(float2*)(og + ((b0 + 1) * NC + n) * ND + d0) = make_float2(ox1, oy1);

    if (last) return;

    // PU[bh] = sum_d out*PE1
    float pu0 = ox0 * p1x + oy0 * p1y;
    float pu1 = ox1 * p1x + oy1 * p1y;
#pragma unroll
    for (int o = 16; o > 0; o >>= 1) { pu0 += __shfl_xor(pu0, o); pu1 += __shfl_xor(pu1, o); }

    // ---- pass 2: logits bl[b,s,n] ----
    float* bl0 = bl + ((b0 + 0) * NS) * NC + n;
    float* bl1 = bl + ((b0 + 1) * NS) * NC + n;
#pragma unroll 2
    for (int s = 0; s < NS; ++s) {
        float2 p  = *(const float2*)(Pp  + s * ND);
        float2 m0 = *(const float2*)(Mp0 + s * ND);
        float2 m1 = *(const float2*)(Mp1 + s * ND);
        float t0 = ox0 * (m0.x + p.x) + oy0 * (m0.y + p.y);
        float t1 = ox1 * (m1.x + p.x) + oy1 * (m1.y + p.y);
#pragma unroll
        for (int o = 16; o > 0; o >>= 1) { t0 += __shfl_xor(t0, o); t1 += __shfl_xor(t1, o); }
        if ((s & 31) == j) {
            bl0[s * NC] = t0 + pu0 * Us[0][s];
            bl1[s * NC] = t1 + pu1 * Us[1][s];
        }
    }
}

// ---------------------------------------------------------------------------
// Softmax over capsule axis n for each (b,s) row; multiplies by mask.
// grid = NB*NS blocks, 128 threads
// ---------------------------------------------------------------------------
__global__ __launch_bounds__(128) void k_softmax(const float* __restrict__ bl,
                                                 const float* __restrict__ mask,
                                                 float* __restrict__ c) {
    int row = blockIdx.x;          // b*NS + s
    int n   = threadIdx.x;         // 0..127
    float v = bl[row * NC + n];

    float mx = v;
#pragma unroll
    for (int o = 32; o > 0; o >>= 1) mx = fmaxf(mx, __shfl_xor(mx, o));
    __shared__ float wmax[2];
    if ((n & 63) == 0) wmax[n >> 6] = mx;
    __syncthreads();
    mx = fmaxf(wmax[0], wmax[1]);

    float e = __expf(v - mx);
    float sm = e;
#pragma unroll
    for (int o = 32; o > 0; o >>= 1) sm += __shfl_xor(sm, o);
    __shared__ float wsum[2];
    if ((n & 63) == 0) wsum[n >> 6] = sm;
    __syncthreads();
    float tot = wsum[0] + wsum[1];

    c[row * NC + n] = e / tot * mask[row];
}

// ---------------------------------------------------------------------------
extern "C" void kernel_launch(void* const* d_in, const int* in_sizes, int n_in,
                              void* d_out, int out_size, void* d_ws, size_t ws_size,
                              hipStream_t stream) {
    const float* u    = (const float*)d_in[0];  // (32,128,256)
    const float* mask = (const float*)d_in[1];  // (32,128)
    const float* W    = (const float*)d_in[2];  // (1,256,64)
    float* out = (float*)d_out;                 // (32,128,64) viewed as (B,N,D)

    float* ws   = (float*)d_ws;
    float* M    = ws;                           // 262144
    float* U    = M + NB * NS * ND;             // 4096
    float* PE1  = U + NB * NS;                  // 8192
    float* pe2n = PE1 + NC * ND;                // 1048576
    float* c    = pe2n + NC * NS * ND;          // 524288
    float* bl   = c + NB * NS * NC;             // 524288

    k_prep<<<5152, 256, 0, stream>>>(u, W, M, U, PE1, pe2n);

    // iter 0 (uniform c = mask/128) -> logits bl
    kA<<<256, 256, 0, stream>>>(M, U, PE1, pe2n, c, mask, out, bl, 1, 0);
    k_softmax<<<NB * NS, 128, 0, stream>>>(bl, mask, c);
    // iter 1 -> logits bl
    kA<<<256, 256, 0, stream>>>(M, U, PE1, pe2n, c, mask, out, bl, 0, 0);
    k_softmax<<<NB * NS, 128, 0, stream>>>(bl, mask, c);
    // iter 2 (final) -> d_out only
    kA<<<256, 256, 0, stream>>>(M, U, PE1, pe2n, c, mask, out, bl, 0, 1);
}

// Round 4
// 135.100 us; speedup vs baseline: 1.6701x; 1.6701x over previous
//
#include <hip/hip_runtime.h>
#include <math.h>

#define NB 32    // batch
#define NS 128   // steps
#define NI 256   // in_dim
#define NC 128   // num capsules
#define ND 64    // dim capsule

#define L4 9.210340371976184f  // ln(10000)

// ---------------------------------------------------------------------------
// k_prep:
//   blocks [0,1024):      M[b,s,d] = sum_i u*W ; U[b,s] = sum_i u
//   blocks [1024,5120):   pe2n[n][s][d]  (n-major trig table)
//   blocks [5120,5152):   PE1[n][d]
// ---------------------------------------------------------------------------
__global__ __launch_bounds__(256) void k_prep(const float* __restrict__ u,
                                              const float* __restrict__ W,
                                              float* __restrict__ M,
                                              float* __restrict__ U,
                                              float* __restrict__ PE1,
                                              float* __restrict__ pe2n) {
    int blk = blockIdx.x;
    int t = threadIdx.x;
    if (blk < 1024) {
        int row = blk * 4 + (t >> 6);   // b*NS + s
        int d = t & 63;
        const float* ur = u + row * NI;
        float acc = 0.f, rs = 0.f;
#pragma unroll 4
        for (int i = 0; i < NI; ++i) {
            float v = ur[i];
            acc = fmaf(v, W[i * ND + d], acc);
            rs += v;
        }
        M[row * ND + d] = acc;
        if (d == 0) U[row] = rs;
    } else if (blk < 1024 + 4096) {
        int idx = (blk - 1024) * 256 + t;          // 1M elems, [n][s][d]
        int n = idx >> 13, s = (idx >> 6) & 127, d = idx & 63;
        int k2 = (n << 5) + (d >> 1);
        float g = __expf(-L4 * (float)k2 * (1.f / 4096.f));
        float sv, cv;
        __sincosf((float)s * g, &sv, &cv);
        pe2n[idx] = (d & 1) ? cv : sv;
    } else {
        int idx = (blk - 1024 - 4096) * 256 + t;   // 8192 elems, [n][d]
        int n = idx >> 6, d = idx & 63;
        float ang = (float)n * __expf(-L4 * (float)(d >> 1) * (1.f / 32.f));
        float sv, cv;
        __sincosf(ang, &sv, &cv);
        PE1[idx] = (d & 1) ? cv : sv;
    }
}

// ---------------------------------------------------------------------------
// kR: one routing iteration, one block per (b,n). 256 threads, ~38.5 KB LDS.
//  build+pass1: thread (sp=t>>4, dq=t&15) builds u4 = M4 + pe1*U + pe2n4 for
//    s = k*16+sp, writes LDS uhT[(dq^(s&15))][s] (b128, 2-way banks) and
//    accumulates acc4 += c[s]*u4 in the same step (no read-back).
//  squash: 16-thread tree on red4; scale kept in LDS (applied lazily).
//  pass2 (if !last): thread (s=t&127, h=t>>7): 8 b128 reads of uhT (XOR
//    derotation) dotted against outs4[dq] (same-addr broadcast); per-s halves
//    combined in LDS; bl[b,n,s] stored coalesced. No butterflies anywhere.
// grid = 4096, LDS-limited to 4 blocks/CU (16 waves).
// ---------------------------------------------------------------------------
__global__ __launch_bounds__(256) void kR(const float* __restrict__ M,
                                          const float* __restrict__ U,
                                          const float* __restrict__ PE1,
                                          const float* __restrict__ pe2n,
                                          const float* __restrict__ cg,
                                          const float* __restrict__ mask,
                                          float* __restrict__ og,
                                          float* __restrict__ bl,
                                          int first, int last) {
    int bn = blockIdx.x;
    int b = bn >> 7, n = bn & 127;
    int t = threadIdx.x;

    __shared__ float4 uhT[16 * 129];     // [j][s], j = dq ^ (s&15), stride 129
    __shared__ float4 red4[16][16];      // pass-1 partials / reused as red2
    __shared__ float4 outs4[16];         // unscaled out_pre, d-quads
    __shared__ float cs_[NS], Us_[NS], ssp[16], scal[1];

    if (t < NS) {
        Us_[t] = U[b * NS + t];
        cs_[t] = first ? mask[b * NS + t] * (1.f / 128.f) : cg[bn * NS + t];
    }
    int dq = t & 15, sp = t >> 4;
    float4 p14 = ((const float4*)PE1)[n * 16 + dq];
    __syncthreads();

    const float4* M4 = (const float4*)M + (b * NS) * 16;
    const float4* P4 = (const float4*)pe2n + (n * NS) * 16;
    float4 acc = make_float4(0.f, 0.f, 0.f, 0.f);
#pragma unroll
    for (int k = 0; k < 8; ++k) {
        int s = k * 16 + sp;
        float4 m4 = M4[s * 16 + dq];
        float4 p4 = P4[s * 16 + dq];
        float uu = Us_[s], cc = cs_[s];
        float4 u4;
        u4.x = fmaf(p14.x, uu, m4.x) + p4.x;
        u4.y = fmaf(p14.y, uu, m4.y) + p4.y;
        u4.z = fmaf(p14.z, uu, m4.z) + p4.z;
        u4.w = fmaf(p14.w, uu, m4.w) + p4.w;
        uhT[(dq ^ (s & 15)) * 129 + s] = u4;
        acc.x = fmaf(cc, u4.x, acc.x);
        acc.y = fmaf(cc, u4.y, acc.y);
        acc.z = fmaf(cc, u4.z, acc.z);
        acc.w = fmaf(cc, u4.w, acc.w);
    }
    red4[sp][dq] = acc;
    __syncthreads();

    if (t < 16) {
        float4 o = make_float4(0.f, 0.f, 0.f, 0.f);
#pragma unroll
        for (int q = 0; q < 16; ++q) {
            float4 r = red4[q][t];
            o.x += r.x; o.y += r.y; o.z += r.z; o.w += r.w;
        }
        outs4[t] = o;
        ssp[t] = o.x * o.x + o.y * o.y + o.z * o.z + o.w * o.w;
    }
    __syncthreads();
    if (t == 0) {
        float ss = 0.f;
#pragma unroll
        for (int j = 0; j < 16; ++j) ss += ssp[j];
        scal[0] = ss / (1.f + ss) * rsqrtf(ss + 1e-7f);
    }
    __syncthreads();
    float scale = scal[0];

    if (last) {
        if (t < 16) {
            float4 o = outs4[t];
            o.x *= scale; o.y *= scale; o.z *= scale; o.w *= scale;
            ((float4*)og)[bn * 16 + t] = o;
        }
        return;
    }

    // pass 2: logits[s] = scale * sum_d out_u[d] * uh[s][d]
    int s = t & 127, h = t >> 7;
    float a2 = 0.f;
#pragma unroll
    for (int i = 0; i < 8; ++i) {
        int dq0 = h * 8 + i;
        float4 u4 = uhT[(dq0 ^ (s & 15)) * 129 + s];
        float4 o4 = outs4[dq0];
        a2 += u4.x * o4.x + u4.y * o4.y + u4.z * o4.z + u4.w * o4.w;
    }
    float* red2 = (float*)red4;
    red2[h * 128 + s] = a2;
    __syncthreads();
    if (t < NS) bl[bn * NS + t] = scale * (red2[t] + red2[128 + t]);
}

// ---------------------------------------------------------------------------
// kS: softmax over n for each (b,s); c[b,n,s] = softmax_n(bl[b,n,s])*mask.
// bl/c layout [b][n][s]. Block = (b, 16-s tile), 256 thr. grid = 256.
// ---------------------------------------------------------------------------
__global__ __launch_bounds__(256) void kS(const float* __restrict__ bl,
                                          const float* __restrict__ mask,
                                          float* __restrict__ c) {
    int blk = blockIdx.x;
    int b = blk >> 3, s0 = (blk & 7) * 16;
    int t = threadIdx.x;

    __shared__ float tl[NC][17];
    __shared__ float pr[16][17];
    __shared__ float ps[16][17];
    __shared__ float itot[16], msk[16];

    if (t < 16) msk[t] = mask[b * NS + s0 + t];
#pragma unroll
    for (int i = 0; i < 8; ++i) {
        int idx = i * 256 + t;
        int n = idx >> 4, si = idx & 15;
        tl[n][si] = bl[(b * NC + n) * NS + s0 + si];
    }
    __syncthreads();

    int si = t & 15, ch = t >> 4;      // 16 chunks x 8 n each
    float mx = -1e30f;
#pragma unroll
    for (int j = 0; j < 8; ++j) mx = fmaxf(mx, tl[ch * 8 + j][si]);
    pr[ch][si] = mx;
    __syncthreads();

    mx = pr[0][si];
#pragma unroll
    for (int jc = 1; jc < 16; ++jc) mx = fmaxf(mx, pr[jc][si]);
    float sm = 0.f;
#pragma unroll
    for (int j = 0; j < 8; ++j) {
        float e = __expf(tl[ch * 8 + j][si] - mx);
        tl[ch * 8 + j][si] = e;       // owner-exclusive rows: no race
        sm += e;
    }
    ps[ch][si] = sm;
    __syncthreads();

    if (t < 16) {
        float tot = 0.f;
#pragma unroll
        for (int jc = 0; jc < 16; ++jc) tot += ps[jc][t];
        itot[t] = msk[t] / tot;
    }
    __syncthreads();

#pragma unroll
    for (int i = 0; i < 8; ++i) {
        int idx = i * 256 + t;
        int n = idx >> 4, sj = idx & 15;
        c[(b * NC + n) * NS + s0 + sj] = tl[n][sj] * itot[sj];
    }
}

// ---------------------------------------------------------------------------
extern "C" void kernel_launch(void* const* d_in, const int* in_sizes, int n_in,
                              void* d_out, int out_size, void* d_ws, size_t ws_size,
                              hipStream_t stream) {
    const float* u    = (const float*)d_in[0];  // (32,128,256)
    const float* mask = (const float*)d_in[1];  // (32,128)
    const float* W    = (const float*)d_in[2];  // (1,256,64)
    float* out = (float*)d_out;                 // (32,128,64) = [b][n][d]

    float* ws   = (float*)d_ws;
    float* M    = ws;                           // 262144
    float* U    = M + NB * NS * ND;             // 4096
    float* PE1  = U + NB * NS;                  // 8192
    float* pe2n = PE1 + NC * ND;                // 1048576
    float* c    = pe2n + NC * NS * ND;          // 524288  [b][n][s]
    float* bl   = c + NB * NC * NS;             // 524288  [b][n][s]

    k_prep<<<5152, 256, 0, stream>>>(u, W, M, U, PE1, pe2n);

    // iter 0 (uniform c = mask/128) -> logits bl
    kR<<<NB * NC, 256, 0, stream>>>(M, U, PE1, pe2n, c, mask, out, bl, 1, 0);
    kS<<<NB * 8, 256, 0, stream>>>(bl, mask, c);
    // iter 1 -> logits bl
    kR<<<NB * NC, 256, 0, stream>>>(M, U, PE1, pe2n, c, mask, out, bl, 0, 0);
    kS<<<NB * 8, 256, 0, stream>>>(bl, mask, c);
    // iter 2 (final) -> d_out
    kR<<<NB * NC, 256, 0, stream>>>(M, U, PE1, pe2n, c, mask, out, bl, 0, 1);
}